// Round 7
// baseline (108.502 us; speedup 1.0000x reference)
//
#include <hip/hip_runtime.h>
#include <hip/hip_bf16.h>

#define TT 8192
#define DIN 512
#define DQK 64

typedef __attribute__((ext_vector_type(8))) short short8;
typedef __attribute__((ext_vector_type(4))) float f32x4;
typedef __attribute__((ext_vector_type(4))) unsigned u32x4;

union S8U4 { u32x4 u; short8 s; };

static __device__ __forceinline__ unsigned pack_bf16(float a, float b) {
    __hip_bfloat16 ha = __float2bfloat16(a);
    __hip_bfloat16 hb = __float2bfloat16(b);
    return (unsigned)(*(unsigned short*)&ha) | ((unsigned)(*(unsigned short*)&hb) << 16);
}

static __device__ __forceinline__ short8 cvt8(const float* p) {
    short tmp[8];
    #pragma unroll
    for (int j = 0; j < 8; ++j) {
        __hip_bfloat16 h = __float2bfloat16(p[j]);
        tmp[j] = *(short*)&h;
    }
    return *(short8*)tmp;
}

// ---------------- zero kernel ----------------
__global__ __launch_bounds__(256) void zero_kernel(float* __restrict__ out, int n4)
{
    int i = blockIdx.x * 256 + threadIdx.x;
    if (i < n4) ((f32x4*)out)[i] = (f32x4){0.f, 0.f, 0.f, 0.f};
}

// ---------------- Kernel 0: W [512][64] f32 -> WT bf16 [3][64][512] ----------------
__global__ __launch_bounds__(256) void wconv_kernel(
    const float* __restrict__ Wq, const float* __restrict__ Wk, const float* __restrict__ Wv,
    __hip_bfloat16* __restrict__ wtb)
{
    __shared__ float tile[64][65];
    const int m = blockIdx.y;
    const float* W = m == 0 ? Wq : (m == 1 ? Wk : Wv);
    const int k0 = blockIdx.x * 64;
    const int tid = threadIdx.x;

    {
        const int col4 = (tid & 15) * 4;
        #pragma unroll
        for (int it = 0; it < 4; ++it) {
            const int row = (tid >> 4) + it * 16;
            float4 v = *(const float4*)&W[(size_t)(k0 + row) * DQK + col4];
            tile[row][col4 + 0] = v.x; tile[row][col4 + 1] = v.y;
            tile[row][col4 + 2] = v.z; tile[row][col4 + 3] = v.w;
        }
    }
    __syncthreads();
    {
        const int d = tid >> 2;
        const int kc = (tid & 3) * 16;
        short tmp[16];
        #pragma unroll
        for (int j = 0; j < 16; ++j) {
            __hip_bfloat16 h = __float2bfloat16(tile[kc + j][d]);
            tmp[j] = *(short*)&h;
        }
        short* dst = (short*)wtb + ((size_t)m * 64 + d) * DIN + k0 + kc;
        *(short8*)dst       = *(short8*)&tmp[0];
        *(short8*)(dst + 8) = *(short8*)&tmp[8];
    }
}

// ---------------- Kernel 1: barrier-free 1-wave MFMA projections ----------------
// block = 1 wave = 16 t-rows; fragments straight from global (x has no reuse).
__global__ __launch_bounds__(64) void proj_kernel(
    const float* __restrict__ x,
    const __hip_bfloat16* __restrict__ wtb,
    __hip_bfloat16* __restrict__ qb, __hip_bfloat16* __restrict__ kb,
    __hip_bfloat16* __restrict__ vt)
{
    __shared__ float tile[16][65];
    const int rowBase = blockIdx.x * 16;
    const int lane = threadIdx.x;
    const int lo = lane & 15, hi = lane >> 4;

    f32x4 acc[3][4];
    #pragma unroll
    for (int m = 0; m < 3; ++m)
        #pragma unroll
        for (int cf = 0; cf < 4; ++cf) acc[m][cf] = (f32x4){0.f, 0.f, 0.f, 0.f};

    const float* xp0 = x + (size_t)(rowBase + lo) * DIN + hi * 8;
    const short* wb0 = (const short*)wtb + (size_t)lo * DIN + hi * 8;

    for (int kk = 0; kk < DIN; kk += 64) {
        float xa[8], xb[8];
        *(float4*)&xa[0] = *(const float4*)(xp0 + kk);
        *(float4*)&xa[4] = *(const float4*)(xp0 + kk + 4);
        *(float4*)&xb[0] = *(const float4*)(xp0 + kk + 32);
        *(float4*)&xb[4] = *(const float4*)(xp0 + kk + 36);
        short8 af0 = cvt8(xa), af1 = cvt8(xb);
        #pragma unroll
        for (int m = 0; m < 3; ++m) {
            #pragma unroll
            for (int cf = 0; cf < 4; ++cf) {
                const short* wp = wb0 + ((size_t)m * 64 + cf * 16) * DIN + kk;
                short8 b0 = *(const short8*)wp;
                short8 b1 = *(const short8*)(wp + 32);
                acc[m][cf] = __builtin_amdgcn_mfma_f32_16x16x32_bf16(af0, b0, acc[m][cf], 0, 0, 0);
                acc[m][cf] = __builtin_amdgcn_mfma_f32_16x16x32_bf16(af1, b1, acc[m][cf], 0, 0, 0);
            }
        }
    }

    // q,k: row-major scalar stores (32B runs per row)
    #pragma unroll
    for (int m = 0; m < 2; ++m) {
        __hip_bfloat16* o = (m == 0) ? qb : kb;
        #pragma unroll
        for (int cf = 0; cf < 4; ++cf)
            #pragma unroll
            for (int r = 0; r < 4; ++r)
                o[(size_t)(rowBase + 4 * hi + r) * DQK + cf * 16 + lo] =
                    __float2bfloat16(acc[m][cf][r]);
    }

    // v: transpose via LDS, vectorized short8 stores to vt[d][t]
    #pragma unroll
    for (int cf = 0; cf < 4; ++cf)
        #pragma unroll
        for (int r = 0; r < 4; ++r)
            tile[4 * hi + r][cf * 16 + lo] = acc[2][cf][r];
    __syncthreads();
    {
        const int d = lane;
        short tmp[16];
        #pragma unroll
        for (int j = 0; j < 16; ++j) {
            __hip_bfloat16 h = __float2bfloat16(tile[j][d]);
            tmp[j] = *(short*)&h;
        }
        short* dst = (short*)vt + (size_t)d * TT + rowBase;
        *(short8*)dst       = *(short8*)&tmp[0];
        *(short8*)(dst + 8) = *(short8*)&tmp[8];
    }
}

// ---------------- Kernel 2: swapped-QK MFMA core, S in registers ----------------
#define TM 128       // t rows per block (8 waves x 16)
#define TS 64        // s per step
#define SCHUNK 256   // s range per block (grid.y)
#define LP 72        // padded LDS row stride (shorts)

__global__ __launch_bounds__(512) void attn_kernel(
    const __hip_bfloat16* __restrict__ qb,
    const __hip_bfloat16* __restrict__ kb,
    const __hip_bfloat16* __restrict__ vt,
    const float* __restrict__ l,
    float* __restrict__ out)
{
    __shared__ short K_lds[2][TS][LP];   // K[s][k], double-buffered
    __shared__ short V_lds[2][DQK][LP];  // Vt[d][s_local], double-buffered

    const int t0 = blockIdx.x * TM;
    const int sStart = blockIdx.y * SCHUNK;
    if (sStart >= t0 + TM) return;
    const int sEnd = min(sStart + SCHUNK, t0 + TM);

    const int tid = threadIdx.x;
    const int lane = tid & 63;
    const int w = tid >> 6;
    const int lo = lane & 15, hi = lane >> 4;
    const int trow = t0 + w * 16;
    const int tmine = trow + lo;       // this lane's t-row (swapped layout: t = lo)

    const int srow = tid >> 3;         // staging: row 0..63
    const int sc8  = (tid & 7) * 8;

    short8 qf0, qf1;
    {
        const short* qp = (const short*)qb + (size_t)tmine * DQK;
        qf0 = *(const short8*)(qp + hi * 8);
        qf1 = *(const short8*)(qp + 32 + hi * 8);
    }

    f32x4 acc_o[4];
    #pragma unroll
    for (int i = 0; i < 4; ++i) acc_o[i] = (f32x4){0.f, 0.f, 0.f, 0.f};

    const float* lrow = l + (size_t)tmine * TT;

    // ---- prologue: tile 0 into buf0; l slice 0 into regs ----
    short8 kreg = *(const short8*)((const short*)kb + (size_t)(sStart + srow) * DQK + sc8);
    short8 vreg = *(const short8*)((const short*)vt + (size_t)srow * TT + sStart + sc8);

    float lvC[4][4];
    if (sStart <= trow + 15) {
        float raw[4][4];
        #pragma unroll
        for (int sub = 0; sub < 4; ++sub)
            *(f32x4*)raw[sub] = __builtin_nontemporal_load(
                (const f32x4*)(lrow + sStart + sub * 16 + 4 * hi));
        if (sStart + 63 <= trow) {
            #pragma unroll
            for (int sub = 0; sub < 4; ++sub)
                #pragma unroll
                for (int r = 0; r < 4; ++r) lvC[sub][r] = raw[sub][r];
        } else {
            #pragma unroll
            for (int sub = 0; sub < 4; ++sub)
                #pragma unroll
                for (int r = 0; r < 4; ++r)
                    lvC[sub][r] = (sStart + sub * 16 + 4 * hi + r <= tmine) ? raw[sub][r] : 0.f;
        }
    }

    *(short8*)&K_lds[0][srow][sc8] = kreg;
    *(short8*)&V_lds[0][srow][sc8] = vreg;
    __syncthreads();

    const int nsteps = (sEnd - sStart) / TS;
    int cur = 0;
    for (int n = 0; n < nsteps; ++n) {
        const int s0 = sStart + n * TS;
        const int sN = s0 + TS;
        const bool havN = (n + 1 < nsteps);
        const bool actN = havN && (sN <= trow + 15);

        // (1) issue l loads for step n+1 (HBM; fly through compute)
        float lvN[4][4];
        if (actN) {
            #pragma unroll
            for (int sub = 0; sub < 4; ++sub)
                *(f32x4*)lvN[sub] = __builtin_nontemporal_load(
                    (const f32x4*)(lrow + sN + sub * 16 + 4 * hi));
        }
        // (2) issue K/V loads for tile n+1 (L2; fly through compute)
        if (havN) {
            kreg = *(const short8*)((const short*)kb + (size_t)(sN + srow) * DQK + sc8);
            vreg = *(const short8*)((const short*)vt + (size_t)srow * TT + sN + sc8);
        }

        // (3) compute step n from LDS[cur]
        if (s0 <= trow + 15) {
            // swapped QK^T: D[s][t], lane holds S[s=s0+16sub+4hi+r][t=tmine]
            unsigned pk[4][2];
            #pragma unroll
            for (int sub = 0; sub < 4; ++sub) {
                short8 b0 = *(short8*)&K_lds[cur][sub * 16 + lo][hi * 8];
                short8 b1 = *(short8*)&K_lds[cur][sub * 16 + lo][32 + hi * 8];
                f32x4 a = (f32x4){0.f, 0.f, 0.f, 0.f};
                a = __builtin_amdgcn_mfma_f32_16x16x32_bf16(b0, qf0, a, 0, 0, 0);
                a = __builtin_amdgcn_mfma_f32_16x16x32_bf16(b1, qf1, a, 0, 0, 0);
                pk[sub][0] = pack_bf16(a[0] * lvC[sub][0], a[1] * lvC[sub][1]);
                pk[sub][1] = pack_bf16(a[2] * lvC[sub][2], a[3] * lvC[sub][3]);
            }
            // in-register transpose to PV A-fragment:
            // a0.dw[2h+p] = pk[hi>>1][p] of lane (lo, 2*(hi&1)+h); a1 from pk[2+(hi>>1)]
            const int srcA = lo | ((lane & 16) << 1);
            unsigned a0dw[4], a1dw[4];
            #pragma unroll
            for (int h = 0; h < 2; ++h) {
                const int src = srcA + 16 * h;
                #pragma unroll
                for (int p = 0; p < 2; ++p) {
                    unsigned u0 = (unsigned)__shfl((int)pk[0][p], src, 64);
                    unsigned u1 = (unsigned)__shfl((int)pk[1][p], src, 64);
                    unsigned u2 = (unsigned)__shfl((int)pk[2][p], src, 64);
                    unsigned u3 = (unsigned)__shfl((int)pk[3][p], src, 64);
                    a0dw[2 * h + p] = (hi < 2) ? u0 : u1;
                    a1dw[2 * h + p] = (hi < 2) ? u2 : u3;
                }
            }
            S8U4 A0, A1;
            A0.u = (u32x4){a0dw[0], a0dw[1], a0dw[2], a0dw[3]};
            A1.u = (u32x4){a1dw[0], a1dw[1], a1dw[2], a1dw[3]};

            // PV: O[t][d] += S[t][s] * V[s][d]
            #pragma unroll
            for (int ds = 0; ds < 4; ++ds) {
                short8 b0 = *(short8*)&V_lds[cur][ds * 16 + lo][hi * 8];
                short8 b1 = *(short8*)&V_lds[cur][ds * 16 + lo][32 + hi * 8];
                acc_o[ds] = __builtin_amdgcn_mfma_f32_16x16x32_bf16(A0.s, b0, acc_o[ds], 0, 0, 0);
                acc_o[ds] = __builtin_amdgcn_mfma_f32_16x16x32_bf16(A1.s, b1, acc_o[ds], 0, 0, 0);
            }
        }

        // (4) write tile n+1 into the other buffer; single barrier per step
        if (havN) {
            *(short8*)&K_lds[cur ^ 1][srow][sc8] = kreg;
            *(short8*)&V_lds[cur ^ 1][srow][sc8] = vreg;
        }
        __syncthreads();
        cur ^= 1;

        // (5) commit masked l for step n+1 (loads have arrived by the barrier)
        if (actN) {
            if (sN + 63 <= trow) {
                #pragma unroll
                for (int sub = 0; sub < 4; ++sub)
                    #pragma unroll
                    for (int r = 0; r < 4; ++r) lvC[sub][r] = lvN[sub][r];
            } else {
                #pragma unroll
                for (int sub = 0; sub < 4; ++sub)
                    #pragma unroll
                    for (int r = 0; r < 4; ++r)
                        lvC[sub][r] = (sN + sub * 16 + 4 * hi + r <= tmine) ? lvN[sub][r] : 0.f;
            }
        }
    }

    // epilogue: D[t=4hi+r][d=ds*16+lo]
    if (sStart <= trow + 15) {
        #pragma unroll
        for (int ds = 0; ds < 4; ++ds) {
            #pragma unroll
            for (int r = 0; r < 4; ++r) {
                const int tg = trow + 4 * hi + r;
                atomicAdd(&out[(size_t)tg * DQK + ds * 16 + lo], acc_o[ds][r]);
            }
        }
    }
}

extern "C" void kernel_launch(void* const* d_in, const int* in_sizes, int n_in,
                              void* d_out, int out_size, void* d_ws, size_t ws_size,
                              hipStream_t stream) {
    const float* x  = (const float*)d_in[0];
    const float* Wq = (const float*)d_in[1];
    const float* Wk = (const float*)d_in[2];
    const float* Wv = (const float*)d_in[3];
    const float* l  = (const float*)d_in[4];
    float* out = (float*)d_out;

    __hip_bfloat16* qb  = (__hip_bfloat16*)d_ws;
    __hip_bfloat16* kb  = qb + (size_t)TT * DQK;
    __hip_bfloat16* vt  = kb + (size_t)TT * DQK;
    __hip_bfloat16* wtb = vt + (size_t)TT * DQK;   // [3][64][512]

    zero_kernel<<<(out_size / 4 + 255) / 256, 256, 0, stream>>>(out, out_size / 4);
    wconv_kernel<<<dim3(DIN / 64, 3), 256, 0, stream>>>(Wq, Wk, Wv, wtb);
    proj_kernel<<<TT / 16, 64, 0, stream>>>(x, wtb, qb, kb, vt);
    attn_kernel<<<dim3(TT / TM, TT / SCHUNK), 512, 0, stream>>>(qb, kb, vt, l, out);
}

// Round 8
// 79.804 us; speedup vs baseline: 1.3596x; 1.3596x over previous
//
#include <hip/hip_runtime.h>
#include <hip/hip_bf16.h>

#define TT 8192
#define DIN 512
#define DQK 64

typedef __attribute__((ext_vector_type(8))) short short8;
typedef __attribute__((ext_vector_type(4))) float f32x4;

// ---------------- zero kernel ----------------
__global__ __launch_bounds__(256) void zero_kernel(float* __restrict__ out, int n4)
{
    int i = blockIdx.x * 256 + threadIdx.x;
    if (i < n4) ((f32x4*)out)[i] = (f32x4){0.f, 0.f, 0.f, 0.f};
}

// ---------------- Kernel 0: W [512][64] f32 -> WT bf16 [3][64][512] ----------------
__global__ __launch_bounds__(256) void wconv_kernel(
    const float* __restrict__ Wq, const float* __restrict__ Wk, const float* __restrict__ Wv,
    __hip_bfloat16* __restrict__ wtb)
{
    __shared__ float tile[64][65];
    const int m = blockIdx.y;
    const float* W = m == 0 ? Wq : (m == 1 ? Wk : Wv);
    const int k0 = blockIdx.x * 64;
    const int tid = threadIdx.x;

    {
        const int col4 = (tid & 15) * 4;
        #pragma unroll
        for (int it = 0; it < 4; ++it) {
            const int row = (tid >> 4) + it * 16;
            float4 v = *(const float4*)&W[(size_t)(k0 + row) * DQK + col4];
            tile[row][col4 + 0] = v.x; tile[row][col4 + 1] = v.y;
            tile[row][col4 + 2] = v.z; tile[row][col4 + 3] = v.w;
        }
    }
    __syncthreads();
    {
        const int d = tid >> 2;
        const int kc = (tid & 3) * 16;
        short tmp[16];
        #pragma unroll
        for (int j = 0; j < 16; ++j) {
            __hip_bfloat16 h = __float2bfloat16(tile[kc + j][d]);
            tmp[j] = *(short*)&h;
        }
        short* dst = (short*)wtb + ((size_t)m * 64 + d) * DIN + k0 + kc;
        *(short8*)dst       = *(short8*)&tmp[0];
        *(short8*)(dst + 8) = *(short8*)&tmp[8];
    }
}

// ---------------- Kernel 1: MFMA projections ----------------
#define PP 72

__global__ __launch_bounds__(256) void proj_kernel(
    const float* __restrict__ x,
    const __hip_bfloat16* __restrict__ wtb,
    __hip_bfloat16* __restrict__ qb, __hip_bfloat16* __restrict__ kb,
    __hip_bfloat16* __restrict__ vt)
{
    __shared__ short xb[64][PP];        // x tile [row][k]
    __shared__ short wb[3][64][PP];     // W^T tiles [m][col(d)][k]

    const int rowBase = blockIdx.x * 64;
    const int tid = threadIdx.x;
    const int lane = tid & 63;
    const int w = tid >> 6;
    const int lo = lane & 15, hi = lane >> 4;

    f32x4 acc[3][4];
    #pragma unroll
    for (int m = 0; m < 3; ++m)
        #pragma unroll
        for (int cf = 0; cf < 4; ++cf) acc[m][cf] = (f32x4){0.f, 0.f, 0.f, 0.f};

    for (int kk = 0; kk < DIN; kk += 64) {
        // stage x 64x64 -> bf16 (vectorized)
        {
            const int r = tid >> 2;
            const int c0 = (tid & 3) * 16;
            const float* xp = x + (size_t)(rowBase + r) * DIN + kk + c0;
            short tmp[16];
            #pragma unroll
            for (int j = 0; j < 16; j += 4) {
                float4 v = *(const float4*)(xp + j);
                __hip_bfloat16 h0 = __float2bfloat16(v.x);
                __hip_bfloat16 h1 = __float2bfloat16(v.y);
                __hip_bfloat16 h2 = __float2bfloat16(v.z);
                __hip_bfloat16 h3 = __float2bfloat16(v.w);
                tmp[j + 0] = *(short*)&h0; tmp[j + 1] = *(short*)&h1;
                tmp[j + 2] = *(short*)&h2; tmp[j + 3] = *(short*)&h3;
            }
            *(short8*)&xb[r][c0]     = *(short8*)&tmp[0];
            *(short8*)&xb[r][c0 + 8] = *(short8*)&tmp[8];
        }
        // stage W^T (already bf16, vector copy)
        {
            const int d = tid >> 2;
            const int kc = (tid & 3) * 16;
            #pragma unroll
            for (int m = 0; m < 3; ++m) {
                const short* src = (const short*)wtb + ((size_t)m * 64 + d) * DIN + kk + kc;
                *(short8*)&wb[m][d][kc]     = *(const short8*)src;
                *(short8*)&wb[m][d][kc + 8] = *(const short8*)(src + 8);
            }
        }
        __syncthreads();

        short8 a0 = *(short8*)&xb[w * 16 + lo][hi * 8];
        short8 a1 = *(short8*)&xb[w * 16 + lo][32 + hi * 8];
        #pragma unroll
        for (int m = 0; m < 3; ++m) {
            #pragma unroll
            for (int cf = 0; cf < 4; ++cf) {
                short8 b0 = *(short8*)&wb[m][cf * 16 + lo][hi * 8];
                short8 b1 = *(short8*)&wb[m][cf * 16 + lo][32 + hi * 8];
                acc[m][cf] = __builtin_amdgcn_mfma_f32_16x16x32_bf16(a0, b0, acc[m][cf], 0, 0, 0);
                acc[m][cf] = __builtin_amdgcn_mfma_f32_16x16x32_bf16(a1, b1, acc[m][cf], 0, 0, 0);
            }
        }
        __syncthreads();
    }

    #pragma unroll
    for (int cf = 0; cf < 4; ++cf) {
        #pragma unroll
        for (int r = 0; r < 4; ++r) {
            const int tg = rowBase + w * 16 + hi * 4 + r;
            const int d  = cf * 16 + lo;
            __hip_bfloat16 hq = __float2bfloat16(acc[0][cf][r]);
            __hip_bfloat16 hk = __float2bfloat16(acc[1][cf][r]);
            __hip_bfloat16 hv = __float2bfloat16(acc[2][cf][r]);
            qb[(size_t)tg * DQK + d] = hq;
            kb[(size_t)tg * DQK + d] = hk;
            vt[(size_t)d * TT + tg]  = hv;
        }
    }
}

// ---------------- Kernel 2: MFMA triangular core (4-wave blocks) ----------------
#define TM 64        // t rows per block (4 waves x 16)
#define TS 64        // s per step
#define SCHUNK 512   // s range per block (grid.y)
#define LP 72        // padded LDS row stride in shorts (144 B)

__global__ __launch_bounds__(256) void attn_kernel(
    const __hip_bfloat16* __restrict__ qb,
    const __hip_bfloat16* __restrict__ kb,
    const __hip_bfloat16* __restrict__ vt,
    const float* __restrict__ l,
    float* __restrict__ out)
{
    __shared__ short K_lds[TS][LP];      // K[s][k]
    __shared__ short V_lds[DQK][LP];     // Vt[d][s_local]
    __shared__ short S_lds[4][16][LP];   // per-wave (wave-private) S[t_loc][s_local]

    const int t0 = blockIdx.x * TM;
    const int sStart = blockIdx.y * SCHUNK;
    if (sStart >= t0 + TM) return;
    const int sEnd = min(sStart + SCHUNK, t0 + TM);

    const int tid = threadIdx.x;
    const int lane = tid & 63;
    const int w = tid >> 6;              // 0..3
    const int lo = lane & 15, hi = lane >> 4;
    const int trow = t0 + w * 16;
    const int r0 = hi * 4;
    const bool waveActive = (sStart <= trow + 15);

    short8 qf0, qf1;
    {
        const short* qp = (const short*)qb + (size_t)(trow + lo) * DQK;
        qf0 = *(const short8*)(qp + hi * 8);
        qf1 = *(const short8*)(qp + 32 + hi * 8);
    }

    f32x4 acc_o[4];
    #pragma unroll
    for (int i = 0; i < 4; ++i) acc_o[i] = (f32x4){0.f, 0.f, 0.f, 0.f};

    // l register double-buffer
    float lvC[4][4];
    float lvN[4][4];
    if (waveActive) {
        #pragma unroll
        for (int sub = 0; sub < 4; ++sub) {
            const int s_glob = sStart + sub * 16 + lo;
            #pragma unroll
            for (int r = 0; r < 4; ++r) {
                const int tg = trow + r0 + r;
                lvC[sub][r] = (s_glob <= tg)
                    ? __builtin_nontemporal_load(&l[(size_t)tg * TT + s_glob]) : 0.f;
            }
        }
    }

    for (int s0 = sStart; s0 < sEnd; s0 += TS) {
        // stage K (64x64) and Vt (64x64): two short8 per thread per matrix
        {
            const int c8 = (tid & 7) * 8;
            #pragma unroll
            for (int it = 0; it < 2; ++it) {
                const int row = (tid >> 3) + it * 32;
                *(short8*)&K_lds[row][c8] =
                    *(const short8*)((const short*)kb + (size_t)(s0 + row) * DQK + c8);
                *(short8*)&V_lds[row][c8] =
                    *(const short8*)((const short*)vt + (size_t)row * TT + s0 + c8);
            }
        }
        __syncthreads();

        const bool active = (s0 <= trow + 15);
        const int sN = s0 + TS;
        const bool act_next = (sN < sEnd) && (sN <= trow + 15);

        // prefetch next step's l slice (flies during MFMA phase)
        if (act_next) {
            if (sN + 63 <= trow) {
                #pragma unroll
                for (int sub = 0; sub < 4; ++sub) {
                    const int s_glob = sN + sub * 16 + lo;
                    #pragma unroll
                    for (int r = 0; r < 4; ++r)
                        lvN[sub][r] = __builtin_nontemporal_load(
                            &l[(size_t)(trow + r0 + r) * TT + s_glob]);
                }
            } else {
                #pragma unroll
                for (int sub = 0; sub < 4; ++sub) {
                    const int s_glob = sN + sub * 16 + lo;
                    #pragma unroll
                    for (int r = 0; r < 4; ++r) {
                        const int tg = trow + r0 + r;
                        lvN[sub][r] = (s_glob <= tg)
                            ? __builtin_nontemporal_load(&l[(size_t)tg * TT + s_glob]) : 0.f;
                    }
                }
            }
        }

        if (active) {
            // QK^T -> *l -> bf16 -> S_lds (wave-private; lgkmcnt only, no barrier)
            #pragma unroll
            for (int sub = 0; sub < 4; ++sub) {
                f32x4 acc = (f32x4){0.f, 0.f, 0.f, 0.f};
                short8 b0 = *(short8*)&K_lds[sub * 16 + lo][hi * 8];
                short8 b1 = *(short8*)&K_lds[sub * 16 + lo][32 + hi * 8];
                acc = __builtin_amdgcn_mfma_f32_16x16x32_bf16(qf0, b0, acc, 0, 0, 0);
                acc = __builtin_amdgcn_mfma_f32_16x16x32_bf16(qf1, b1, acc, 0, 0, 0);
                #pragma unroll
                for (int r = 0; r < 4; ++r) {
                    float sv = acc[r] * lvC[sub][r];
                    __hip_bfloat16 h = __float2bfloat16(sv);
                    S_lds[w][r0 + r][sub * 16 + lo] = *(short*)&h;
                }
            }
            // PV
            short8 a0 = *(short8*)&S_lds[w][lo][hi * 8];
            short8 a1 = *(short8*)&S_lds[w][lo][32 + hi * 8];
            #pragma unroll
            for (int ds = 0; ds < 4; ++ds) {
                short8 b0 = *(short8*)&V_lds[ds * 16 + lo][hi * 8];
                short8 b1 = *(short8*)&V_lds[ds * 16 + lo][32 + hi * 8];
                acc_o[ds] = __builtin_amdgcn_mfma_f32_16x16x32_bf16(a0, b0, acc_o[ds], 0, 0, 0);
                acc_o[ds] = __builtin_amdgcn_mfma_f32_16x16x32_bf16(a1, b1, acc_o[ds], 0, 0, 0);
            }
        }
        __syncthreads();

        #pragma unroll
        for (int sub = 0; sub < 4; ++sub)
            #pragma unroll
            for (int r = 0; r < 4; ++r)
                lvC[sub][r] = lvN[sub][r];
    }

    if (waveActive) {
        #pragma unroll
        for (int ds = 0; ds < 4; ++ds) {
            #pragma unroll
            for (int r = 0; r < 4; ++r) {
                const int tg = trow + r0 + r;
                atomicAdd(&out[(size_t)tg * DQK + ds * 16 + lo], acc_o[ds][r]);
            }
        }
    }
}

extern "C" void kernel_launch(void* const* d_in, const int* in_sizes, int n_in,
                              void* d_out, int out_size, void* d_ws, size_t ws_size,
                              hipStream_t stream) {
    const float* x  = (const float*)d_in[0];
    const float* Wq = (const float*)d_in[1];
    const float* Wk = (const float*)d_in[2];
    const float* Wv = (const float*)d_in[3];
    const float* l  = (const float*)d_in[4];
    float* out = (float*)d_out;

    __hip_bfloat16* qb  = (__hip_bfloat16*)d_ws;
    __hip_bfloat16* kb  = qb + (size_t)TT * DQK;
    __hip_bfloat16* vt  = kb + (size_t)TT * DQK;
    __hip_bfloat16* wtb = vt + (size_t)TT * DQK;   // [3][64][512]

    zero_kernel<<<(out_size / 4 + 255) / 256, 256, 0, stream>>>(out, out_size / 4);
    wconv_kernel<<<dim3(DIN / 64, 3), 256, 0, stream>>>(Wq, Wk, Wv, wtb);
    proj_kernel<<<TT / 64, 256, 0, stream>>>(x, wtb, qb, kb, vt);
    attn_kernel<<<dim3(TT / TM, TT / SCHUNK), 256, 0, stream>>>(qb, kb, vt, l, out);
}